// Round 1
// baseline (908.246 us; speedup 1.0000x reference)
//
#include <hip/hip_runtime.h>

#define USER_NUM 500000
#define BATCH 4096
#define NF 64
#define DIM 256
#define MEMN 32
#define ATTN 256

typedef short bf16x8 __attribute__((ext_vector_type(8)));
typedef float f32x4 __attribute__((ext_vector_type(4)));

// ---------- bf16 helpers (RNE) ----------
__device__ __forceinline__ unsigned short f2bf(float f) {
    unsigned u = __float_as_uint(f);
    u += 0x7FFFu + ((u >> 16) & 1u);
    return (unsigned short)(u >> 16);
}
__device__ __forceinline__ float bf2f(unsigned short s) {
    return __uint_as_float(((unsigned)s) << 16);
}

__device__ __forceinline__ float block_reduce_sum(float v, float* scr) {
#pragma unroll
    for (int o = 32; o; o >>= 1) v += __shfl_xor(v, o, 64);
    __syncthreads();
    if ((threadIdx.x & 63) == 0) scr[threadIdx.x >> 6] = v;
    __syncthreads();
    return scr[0] + scr[1] + scr[2] + scr[3];
}

// ---------- ws offsets (bytes) ----------
#define WS_AK    0u           // float [4096][64][32]   = 33554432
#define WS_KEYT  33554432u    // bf16  [32][256]        = 16384  (KeyT[m][d])
#define WS_MEMT  33570816u    // bf16  [256][32]        = 16384  (MemT[d][m])
#define WS_WATT  33587200u    // bf16  [8][256][32]     = 131072 (WA k-tiled: [kt][a][kk])
#define WS_PART  33718272u    // float [8][2048]        = 65536
#define WS_SSUM  33783808u    // float [2048]           = 8192

// =============== kernel P: transpose/convert constants to bf16 ===============
__global__ __launch_bounds__(256) void kprep(const float* __restrict__ Key,
                                             const float* __restrict__ Mem,
                                             const float* __restrict__ WA,
                                             unsigned short* __restrict__ keyT,
                                             unsigned short* __restrict__ memT,
                                             unsigned short* __restrict__ watt) {
    int gid = blockIdx.x * 256 + threadIdx.x;   // grid = 320 blocks -> 81920 exactly
    if (gid < 8192) {                 // KeyT[m][d] = Key[d][m]
        int m = gid >> 8, d = gid & 255;
        keyT[gid] = f2bf(Key[d * 32 + m]);
    } else if (gid < 16384) {         // MemT[d][m] = Mem[m][d]
        int e = gid - 8192, d = e >> 5, m = e & 31;
        memT[e] = f2bf(Mem[m * 256 + d]);
    } else {                          // watt[kt][a][kk] = WA[kt*32+kk][a]
        int e = gid - 16384;
        int kt = e >> 13, r = e & 8191, a = r >> 5, kk = r & 31;
        watt[e] = f2bf(WA[(kt * 32 + kk) * 256 + a]);
    }
}

// =============== kernel A: att_key[b,f,m] (one block per b) ===============
// LDS: cross bf16 [64][264] @0 (33792) | keyT bf16 [32][264] @33792 (16896)
//      uidn f32 [256] @50688 | scr @51712   -> 51776 dynamic
__global__ __launch_bounds__(256) void katt(const int* __restrict__ input_u,
                                            const int* __restrict__ input_uf,
                                            const float* __restrict__ uidW,
                                            const unsigned short* __restrict__ keyT_ws,
                                            float* __restrict__ ak) {
    extern __shared__ char smem[];
    float* uidn = (float*)(smem + 50688);
    float* scr  = (float*)(smem + 51712);
    const int b = blockIdx.x, t = threadIdx.x;
    const int w = t >> 6, l = t & 63;

    // stage KeyT (bf16, padded rows of 264 elems = 528 B)
    {
        const uint4* src = (const uint4*)keyT_ws;
#pragma unroll
        for (int k = 0; k < 4; k++) {
            int ci = t + 256 * k;           // 1024 chunks of 16B
            int m = ci >> 5, c = ci & 31;
            *(uint4*)(smem + 33792 + m * 528 + c * 16) = src[ci];
        }
    }
    // uid row + L2 normalize
    int iu = input_u[b];
    float uv = uidW[(size_t)iu * DIM + t];
    float ss = block_reduce_sum(uv * uv, scr);
    float inv = 1.0f / fmaxf(sqrtf(ss), 1e-12f);
    uidn[t] = uv * inv;
    __syncthreads();

    // gather fe, normalize, cross = uid_n * fe_n  -> LDS bf16 (wave w: f = 16w..16w+15)
    float4 un4 = *(const float4*)(uidn + l * 4);
    for (int i = 0; i < 16; i++) {
        int f = w * 16 + i;
        int idx = input_uf[b * NF + f];
        float mk = (idx != USER_NUM) ? 1.0f : 0.0f;
        float4 fe = ((const float4*)(uidW + (size_t)idx * DIM))[l];
        fe.x *= mk; fe.y *= mk; fe.z *= mk; fe.w *= mk;
        float s2 = fe.x * fe.x + fe.y * fe.y + fe.z * fe.z + fe.w * fe.w;
#pragma unroll
        for (int o = 32; o; o >>= 1) s2 += __shfl_xor(s2, o, 64);
        float rn = 1.0f / fmaxf(sqrtf(s2), 1e-12f);
        ushort4 o4;
        o4.x = f2bf(un4.x * fe.x * rn);
        o4.y = f2bf(un4.y * fe.y * rn);
        o4.z = f2bf(un4.z * fe.z * rn);
        o4.w = f2bf(un4.w * fe.w * rn);
        *(ushort4*)(smem + f * 528 + l * 8) = o4;
    }
    __syncthreads();

    // MFMA: att_key[64f x 32m] = cross[64x256] @ Key[256x32]; wave w owns f-tile w
    bf16x8 aF[8];
#pragma unroll
    for (int k = 0; k < 8; k++)
        aF[k] = *(const bf16x8*)(smem + (w * 16 + (l & 15)) * 528 + k * 64 + (l >> 4) * 16);
#pragma unroll
    for (int mt = 0; mt < 2; mt++) {
        f32x4 acc = {0.f, 0.f, 0.f, 0.f};
#pragma unroll
        for (int k = 0; k < 8; k++) {
            bf16x8 bF = *(const bf16x8*)(smem + 33792 + (mt * 16 + (l & 15)) * 528 + k * 64 + (l >> 4) * 16);
            acc = __builtin_amdgcn_mfma_f32_16x16x32_bf16(aF[k], bF, acc, 0, 0, 0);
        }
        int m = mt * 16 + (l & 15);
        int fbase = w * 16 + (l >> 4) * 4;
#pragma unroll
        for (int r = 0; r < 4; r++)
            ak[((size_t)b * NF + fbase + r) * MEMN + m] = acc[r];
    }
}

// =============== kernel B1/B2: ssum[f,m] = sum_b exp(ak[b,f,m]) ===============
__global__ __launch_bounds__(256) void ksum1(const float* __restrict__ ak, float* __restrict__ part) {
    __shared__ float pl[256];
    int bid = blockIdx.x;               // 512 = 64 f * 8 chunks
    int f = bid >> 3, c = bid & 7;
    int t = threadIdx.x, m = t & 31, g = t >> 5;
    float s = 0.f;
    size_t base = ((size_t)(c * 512 + g) * NF + f) * MEMN + m;
    for (int i = 0; i < 64; i++) {      // b = c*512 + g + 8*i
        s += __expf(ak[base]);
        base += (size_t)8 * NF * MEMN;
    }
    pl[t] = s;
    __syncthreads();
    if (t < 32) {
        float tot = 0.f;
#pragma unroll
        for (int gg = 0; gg < 8; gg++) tot += pl[gg * 32 + t];
        part[c * 2048 + f * 32 + t] = tot;
    }
}
__global__ __launch_bounds__(256) void ksum2(const float* __restrict__ part, float* __restrict__ ssum) {
    int fm = blockIdx.x * 256 + threadIdx.x;   // 8 blocks
    float s = 0.f;
#pragma unroll
    for (int c = 0; c < 8; c++) s += part[c * 2048 + fm];
    ssum[fm] = s;
}

// =============== kernel C: everything after the batch softmax (one block per b) ===============
// LDS layout (bytes):
//   f1f2 bf16 [64][264] @0      (33792)   f1 then overwritten by f2
//   am   bf16 [64][40]  @33792  (5120)
//   memT bf16 [256][40] @38912  (20480)
//   wat  bf16 [256][40] @33792  (20480)  aliases am+memT (dead after f1-GEMM)
//   jpart f32 [4][64]   @59392  (1024)
//   wL    f32 [64]      @60416  (256)
//   ufL   i32 [64]      @60672  (256)
//   mskL  f32 [64]      @60928  (256)
//   scr   f32 [16]      @61184           -> 61440 dynamic
#define OFF_AM   33792
#define OFF_MEMT 38912
#define OFF_WAT  33792
#define OFF_JP   59392
#define OFF_W    60416
#define OFF_UF   60672
#define OFF_MSK  60928
#define OFF_SCR  61184
__global__ __launch_bounds__(256) void kmain(const int* __restrict__ input_u,
                                             const int* __restrict__ input_i,
                                             const int* __restrict__ input_uf,
                                             const float* __restrict__ uidW,
                                             const float* __restrict__ iidW,
                                             const float* __restrict__ i_bias,
                                             const float* __restrict__ BA,
                                             const float* __restrict__ U_omega,
                                             const float* __restrict__ att_exp1,
                                             const float* __restrict__ ak,
                                             const float* __restrict__ ssum_ws,
                                             const unsigned short* __restrict__ memT_ws,
                                             const unsigned short* __restrict__ watt_ws,
                                             float* __restrict__ out) {
    extern __shared__ char smem[];
    float* jpL  = (float*)(smem + OFF_JP);
    float* wL   = (float*)(smem + OFF_W);
    int*   ufL  = (int*)(smem + OFF_UF);
    float* mskL = (float*)(smem + OFF_MSK);
    float* scr  = (float*)(smem + OFF_SCR);
    const int b = blockIdx.x, t = threadIdx.x;
    const int w = t >> 6, l = t & 63;

    // early global loads (latency hiding; used in final phase)
    int iu = input_u[b], ii = input_i[b];
    float uidv = uidW[(size_t)iu * DIM + t];
    float iidv = iidW[(size_t)ii * DIM + t];
    float ib   = i_bias[ii];
    float ae00 = att_exp1[t * 2], ae01 = att_exp1[t * 2 + 1];
    float ae10 = att_exp1[(DIM + t) * 2], ae11 = att_exp1[(DIM + t) * 2 + 1];

    // ph0: friend ids + masks, stage MemT
    if (t < 64) {
        int uf = input_uf[b * NF + t];
        ufL[t] = uf;
        mskL[t] = (uf != USER_NUM) ? 1.0f : 0.0f;
    }
    {
        const uint4* src = (const uint4*)memT_ws;
#pragma unroll
        for (int k = 0; k < 4; k++) {
            int ci = t + 256 * k;            // 1024 chunks
            int d = ci >> 2, c = ci & 3;
            *(uint4*)(smem + OFF_MEMT + d * 80 + c * 16) = src[ci];
        }
    }
    __syncthreads();

    // ph1: att_mem = mask * exp(ak)/ssum -> LDS bf16 (A-operand of f1 GEMM)
    {
        const float4* akp = (const float4*)(ak + (size_t)b * 2048);
        const float4* sp  = (const float4*)ssum_ws;
        float4 a0 = akp[2 * t], a1 = akp[2 * t + 1];
        float4 s0 = sp[2 * t],  s1 = sp[2 * t + 1];
        float mk = mskL[t >> 2];
        float v0 = mk * __expf(a0.x) / s0.x;
        float v1 = mk * __expf(a0.y) / s0.y;
        float v2 = mk * __expf(a0.z) / s0.z;
        float v3 = mk * __expf(a0.w) / s0.w;
        float v4 = mk * __expf(a1.x) / s1.x;
        float v5 = mk * __expf(a1.y) / s1.y;
        float v6 = mk * __expf(a1.z) / s1.z;
        float v7 = mk * __expf(a1.w) / s1.w;
        uint4 pk;
        pk.x = (unsigned)f2bf(v0) | ((unsigned)f2bf(v1) << 16);
        pk.y = (unsigned)f2bf(v2) | ((unsigned)f2bf(v3) << 16);
        pk.z = (unsigned)f2bf(v4) | ((unsigned)f2bf(v5) << 16);
        pk.w = (unsigned)f2bf(v6) | ((unsigned)f2bf(v7) << 16);
        *(uint4*)(smem + OFF_AM + (t >> 2) * 80 + (t & 3) * 16) = pk;
    }
    __syncthreads();

    // ph2: f1[64f x 256d] = am[64x32] @ Mem[32x256]  (wave w owns d in [64w,64w+64))
    {
        bf16x8 aF[4];
#pragma unroll
        for (int ft = 0; ft < 4; ft++)
            aF[ft] = *(const bf16x8*)(smem + OFF_AM + (ft * 16 + (l & 15)) * 80 + (l >> 4) * 16);
#pragma unroll
        for (int dti = 0; dti < 4; dti++) {
            int dt = 4 * w + dti;
            bf16x8 bF = *(const bf16x8*)(smem + OFF_MEMT + (dt * 16 + (l & 15)) * 80 + (l >> 4) * 16);
            int dcol = dt * 16 + (l & 15);
#pragma unroll
            for (int ft = 0; ft < 4; ft++) {
                f32x4 acc = {0.f, 0.f, 0.f, 0.f};
                acc = __builtin_amdgcn_mfma_f32_16x16x32_bf16(aF[ft], bF, acc, 0, 0, 0);
                int fbase = ft * 16 + (l >> 4) * 4;
#pragma unroll
                for (int r = 0; r < 4; r++)
                    *(unsigned short*)(smem + (fbase + r) * 528 + dcol * 2) = f2bf(acc[r]);
            }
        }
    }
    __syncthreads();

    // ph3: regather fe; f2 = f1 * fe * mask (overwrite in place)
    for (int i = 0; i < 16; i++) {
        int f = w * 16 + i;
        int idx = ufL[f];
        float mk = mskL[f];
        float4 fe = ((const float4*)(uidW + (size_t)idx * DIM))[l];
        ushort4* p = (ushort4*)(smem + f * 528 + l * 8);
        ushort4 q = *p;
        ushort4 o4;
        o4.x = f2bf(bf2f(q.x) * fe.x * mk);
        o4.y = f2bf(bf2f(q.y) * fe.y * mk);
        o4.z = f2bf(bf2f(q.z) * fe.z * mk);
        o4.w = f2bf(bf2f(q.w) * fe.w * mk);
        *p = o4;
    }
    __syncthreads();

    // ph4: H = relu(f2 @ WA + BA); logits j_f = sum_a H*Uw. Wave w owns a in [64w,64w+64).
    f32x4 acc[4][4];
    {
        f32x4 z = {0.f, 0.f, 0.f, 0.f};
#pragma unroll
        for (int ft = 0; ft < 4; ft++)
#pragma unroll
            for (int at = 0; at < 4; at++) acc[ft][at] = z;
    }
    for (int kt = 0; kt < 8; kt++) {
        const uint4* src = ((const uint4*)watt_ws) + kt * 1024;
#pragma unroll
        for (int k = 0; k < 4; k++) {
            int ci = t + 256 * k;
            int a = ci >> 2, c = ci & 3;
            *(uint4*)(smem + OFF_WAT + a * 80 + c * 16) = src[ci];
        }
        __syncthreads();
        bf16x8 aF[4], bF[4];
#pragma unroll
        for (int ft = 0; ft < 4; ft++)
            aF[ft] = *(const bf16x8*)(smem + (ft * 16 + (l & 15)) * 528 + kt * 64 + (l >> 4) * 16);
#pragma unroll
        for (int at = 0; at < 4; at++)
            bF[at] = *(const bf16x8*)(smem + OFF_WAT + (64 * w + at * 16 + (l & 15)) * 80 + (l >> 4) * 16);
#pragma unroll
        for (int ft = 0; ft < 4; ft++)
#pragma unroll
            for (int at = 0; at < 4; at++)
                acc[ft][at] = __builtin_amdgcn_mfma_f32_16x16x32_bf16(aF[ft], bF[at], acc[ft][at], 0, 0, 0);
        __syncthreads();
    }
    {
        float jp[16];
#pragma unroll
        for (int i = 0; i < 16; i++) jp[i] = 0.f;
#pragma unroll
        for (int at = 0; at < 4; at++) {
            int a = 64 * w + at * 16 + (l & 15);
            float ba = BA[a], uw = U_omega[a];
#pragma unroll
            for (int ft = 0; ft < 4; ft++)
#pragma unroll
                for (int r = 0; r < 4; r++) {
                    float h = fmaxf(acc[ft][at][r] + ba, 0.f);
                    jp[ft * 4 + r] += h * uw;
                }
        }
#pragma unroll
        for (int mask = 1; mask < 16; mask <<= 1)
#pragma unroll
            for (int i = 0; i < 16; i++) jp[i] += __shfl_xor(jp[i], mask, 64);
        if ((l & 15) == 0) {
#pragma unroll
            for (int ft = 0; ft < 4; ft++)
#pragma unroll
                for (int r = 0; r < 4; r++)
                    jpL[w * 64 + ft * 16 + (l >> 4) * 4 + r] = jp[ft * 4 + r];
        }
    }
    __syncthreads();

    // ph5: friend weights w_f = mask*exp(logit) / (sum + 1e-8)
    if (t < 64) {
        float logit = jpL[t] + jpL[64 + t] + jpL[128 + t] + jpL[192 + t];
        float jv = mskL[t] * __expf(logit);
        float s = jv;
#pragma unroll
        for (int o = 32; o; o >>= 1) s += __shfl_xor(s, o, 64);
        wL[t] = jv / (s + 1e-8f);
    }
    __syncthreads();

    // ph6: friend[d] = sum_f w_f * f2[f][d]
    float fr = 0.f;
#pragma unroll 8
    for (int f = 0; f < 64; f++)
        fr += wL[f] * bf2f(*(unsigned short*)(smem + f * 528 + t * 2));

    // ph7: user attention + score
    float user = uidv + fr;
    float l0 = block_reduce_sum(uidv * ae00 + user * ae10, scr);
    float l1 = block_reduce_sum(uidv * ae01 + user * ae11, scr);
    float mx = fmaxf(l0, l1);
    float e0 = __expf(l0 - mx), e1 = __expf(l1 - mx);
    float rinv = 1.0f / (e0 + e1);
    float a0w = e0 * rinv, a1w = e1 * rinv;
    float sc = block_reduce_sum((uidv * a0w + user * a1w) * iidv, scr);
    if (t == 0) out[b] = sc + ib;
}

extern "C" void kernel_launch(void* const* d_in, const int* in_sizes, int n_in,
                              void* d_out, int out_size, void* d_ws, size_t ws_size,
                              hipStream_t stream) {
    const int*   input_u  = (const int*)d_in[0];
    const int*   input_i  = (const int*)d_in[1];
    const int*   input_uf = (const int*)d_in[2];
    const float* uidW     = (const float*)d_in[3];
    const float* iidW     = (const float*)d_in[4];
    const float* i_bias   = (const float*)d_in[5];
    const float* Key      = (const float*)d_in[6];
    const float* Mem      = (const float*)d_in[7];
    const float* WA       = (const float*)d_in[8];
    const float* BA       = (const float*)d_in[9];
    const float* U_omega  = (const float*)d_in[10];
    const float* att_exp1 = (const float*)d_in[11];
    float* out = (float*)d_out;
    char* ws = (char*)d_ws;

    float*          ak   = (float*)(ws + WS_AK);
    unsigned short* keyT = (unsigned short*)(ws + WS_KEYT);
    unsigned short* memT = (unsigned short*)(ws + WS_MEMT);
    unsigned short* watt = (unsigned short*)(ws + WS_WATT);
    float*          part = (float*)(ws + WS_PART);
    float*          ssum = (float*)(ws + WS_SSUM);

    hipLaunchKernelGGL(kprep, dim3(320), dim3(256), 0, stream, Key, Mem, WA, keyT, memT, watt);
    hipLaunchKernelGGL(katt, dim3(BATCH), dim3(256), 51776, stream, input_u, input_uf, uidW, keyT, ak);
    hipLaunchKernelGGL(ksum1, dim3(512), dim3(256), 0, stream, ak, part);
    hipLaunchKernelGGL(ksum2, dim3(8), dim3(256), 0, stream, part, ssum);
    hipLaunchKernelGGL(kmain, dim3(BATCH), dim3(256), 61440, stream, input_u, input_i, input_uf,
                       uidW, iidW, i_bias, BA, U_omega, att_exp1, ak, ssum, memT, watt, out);
}

// Round 2
// 802.047 us; speedup vs baseline: 1.1324x; 1.1324x over previous
//
#include <hip/hip_runtime.h>

#define USER_NUM 500000
#define BATCH 4096
#define NF 64
#define DIM 256
#define MEMN 32
#define ATTN 256

typedef short bf16x8 __attribute__((ext_vector_type(8)));
typedef float f32x4 __attribute__((ext_vector_type(4)));

// ---------- bf16 helpers (RNE) ----------
__device__ __forceinline__ unsigned short f2bf(float f) {
    unsigned u = __float_as_uint(f);
    u += 0x7FFFu + ((u >> 16) & 1u);
    return (unsigned short)(u >> 16);
}
__device__ __forceinline__ float bf2f(unsigned short s) {
    return __uint_as_float(((unsigned)s) << 16);
}
__device__ __forceinline__ bf16x8 as_frag(uint4 v) {
    return __builtin_bit_cast(bf16x8, v);
}

__device__ __forceinline__ float block_reduce_sum(float v, float* scr) {
#pragma unroll
    for (int o = 32; o; o >>= 1) v += __shfl_xor(v, o, 64);
    __syncthreads();
    if ((threadIdx.x & 63) == 0) scr[threadIdx.x >> 6] = v;
    __syncthreads();
    return scr[0] + scr[1] + scr[2] + scr[3];
}

// ---------- ws offsets (bytes) ----------
#define WS_AK    0u            // float [4096][64][32]     = 33554432
#define WS_FE    33554432u     // bf16  [4096][64][256]    = 134217728 (masked fe)
#define WS_KEYT  167772160u    // bf16  [32][256]          = 16384  (KeyT[m][d])
#define WS_MEMT  167788544u    // bf16  [256][32]          = 16384  (MemT[d][m])
#define WS_WATT  167804928u    // bf16  [8][256][32]       = 131072 (WA k-tiled: [kt][a][kk])
#define WS_PART  167936000u    // float [8][2048]          = 65536
#define WS_SSUM  168001536u    // float [2048]             = 8192

// =============== kernel P: transpose/convert constants to bf16 ===============
__global__ __launch_bounds__(256) void kprep(const float* __restrict__ Key,
                                             const float* __restrict__ Mem,
                                             const float* __restrict__ WA,
                                             unsigned short* __restrict__ keyT,
                                             unsigned short* __restrict__ memT,
                                             unsigned short* __restrict__ watt) {
    int gid = blockIdx.x * 256 + threadIdx.x;   // grid = 320 blocks -> 81920 exactly
    if (gid < 8192) {                 // KeyT[m][d] = Key[d][m]
        int m = gid >> 8, d = gid & 255;
        keyT[gid] = f2bf(Key[d * 32 + m]);
    } else if (gid < 16384) {         // MemT[d][m] = Mem[m][d]
        int e = gid - 8192, d = e >> 5, m = e & 31;
        memT[e] = f2bf(Mem[m * 256 + d]);
    } else {                          // watt[kt][a][kk] = WA[kt*32+kk][a]
        int e = gid - 16384;
        int kt = e >> 13, r = e & 8191, a = r >> 5, kk = r & 31;
        watt[e] = f2bf(WA[(kt * 32 + kk) * 256 + a]);
    }
}

// =============== kernel A: att_key[b,f,m] + fe_bf16 dump (one block per b) ===============
// LDS: cross bf16 [64][264] @0 (33792) | uidn f32 [256] @33792 | scr @34816
//      ufL i32[64] @34880 | mskL f32[64] @35136  -> 35392 dynamic
__global__ __launch_bounds__(256, 4) void katt(const int* __restrict__ input_u,
                                               const int* __restrict__ input_uf,
                                               const float* __restrict__ uidW,
                                               const unsigned short* __restrict__ keyT_ws,
                                               unsigned short* __restrict__ fe_ws,
                                               float* __restrict__ ak) {
    extern __shared__ char smem[];
    float* uidn = (float*)(smem + 33792);
    float* scr  = (float*)(smem + 34816);
    int*   ufL  = (int*)(smem + 34880);
    float* mskL = (float*)(smem + 35136);
    const int b = blockIdx.x, t = threadIdx.x;
    const int w = t >> 6, l = t & 63, q = l >> 4;

    if (t < 64) {
        int uf = input_uf[b * NF + t];
        ufL[t] = uf;
        mskL[t] = (uf != USER_NUM) ? 1.0f : 0.0f;
    }
    // uid row + L2 normalize (block_reduce's barriers also publish ufL/mskL)
    int iu = input_u[b];
    float uv = uidW[(size_t)iu * DIM + t];
    float ss = block_reduce_sum(uv * uv, scr);
    float inv = 1.0f / fmaxf(sqrtf(ss), 1e-12f);
    uidn[t] = uv * inv;
    __syncthreads();

    // gather all 16 friend rows for this wave with max MLP, then normalize
    float4 un4 = *(const float4*)(uidn + l * 4);
    float4 fe[16];
#pragma unroll
    for (int i = 0; i < 16; i++) {
        int idx = ufL[w * 16 + i];
        fe[i] = ((const float4*)(uidW + (size_t)idx * DIM))[l];
    }
#pragma unroll
    for (int i = 0; i < 16; i++) {
        int f = w * 16 + i;
        float mk = mskL[f];
        float x = fe[i].x * mk, y = fe[i].y * mk, z = fe[i].z * mk, ww = fe[i].w * mk;
        float s2 = x * x + y * y + z * z + ww * ww;
#pragma unroll
        for (int o = 32; o; o >>= 1) s2 += __shfl_xor(s2, o, 64);
        float rn = 1.0f / fmaxf(sqrtf(s2), 1e-12f);
        // masked fe -> ws (bf16, sequential)
        ushort4 fb;
        fb.x = f2bf(x); fb.y = f2bf(y); fb.z = f2bf(z); fb.w = f2bf(ww);
        *(ushort4*)(fe_ws + (size_t)b * 16384 + f * 256 + l * 4) = fb;
        // cross = uid_n * fe_n -> LDS
        ushort4 o4;
        o4.x = f2bf(un4.x * x * rn);
        o4.y = f2bf(un4.y * y * rn);
        o4.z = f2bf(un4.z * z * rn);
        o4.w = f2bf(un4.w * ww * rn);
        *(ushort4*)(smem + f * 528 + l * 8) = o4;
    }
    __syncthreads();

    // MFMA: att_key[64f x 32m] = cross[64x256] @ Key[256x32]; wave w owns f-tile w.
    // Key B-frags straight from L2-hot ws (no LDS staging, no extra barrier).
    const uint4* kp = (const uint4*)keyT_ws;   // [m][d] rows of 512B = 32 uint4
    f32x4 acc0 = {0.f, 0.f, 0.f, 0.f}, acc1 = {0.f, 0.f, 0.f, 0.f};
#pragma unroll
    for (int kt = 0; kt < 8; kt++) {
        bf16x8 aF = *(const bf16x8*)(smem + (w * 16 + (l & 15)) * 528 + kt * 64 + q * 16);
        bf16x8 b0 = as_frag(kp[(l & 15) * 32 + kt * 4 + q]);
        bf16x8 b1 = as_frag(kp[((l & 15) + 16) * 32 + kt * 4 + q]);
        acc0 = __builtin_amdgcn_mfma_f32_16x16x32_bf16(aF, b0, acc0, 0, 0, 0);
        acc1 = __builtin_amdgcn_mfma_f32_16x16x32_bf16(aF, b1, acc1, 0, 0, 0);
    }
    {
        int fbase = w * 16 + q * 4;
        int m = l & 15;
#pragma unroll
        for (int r = 0; r < 4; r++) {
            ak[((size_t)b * NF + fbase + r) * MEMN + m]      = acc0[r];
            ak[((size_t)b * NF + fbase + r) * MEMN + 16 + m] = acc1[r];
        }
    }
}

// =============== kernel B1/B2: ssum[f,m] = sum_b exp(ak[b,f,m]) ===============
__global__ __launch_bounds__(256) void ksum1(const float* __restrict__ ak, float* __restrict__ part) {
    __shared__ float pl[256];
    int bid = blockIdx.x;               // 512 = 64 f * 8 chunks
    int f = bid >> 3, c = bid & 7;
    int t = threadIdx.x, m = t & 31, g = t >> 5;
    float s = 0.f;
    size_t base = ((size_t)(c * 512 + g) * NF + f) * MEMN + m;
    for (int i = 0; i < 64; i++) {      // b = c*512 + g + 8*i
        s += __expf(ak[base]);
        base += (size_t)8 * NF * MEMN;
    }
    pl[t] = s;
    __syncthreads();
    if (t < 32) {
        float tot = 0.f;
#pragma unroll
        for (int gg = 0; gg < 8; gg++) tot += pl[gg * 32 + t];
        part[c * 2048 + f * 32 + t] = tot;
    }
}
__global__ __launch_bounds__(256) void ksum2(const float* __restrict__ part, float* __restrict__ ssum) {
    int fm = blockIdx.x * 256 + threadIdx.x;   // 8 blocks
    float s = 0.f;
#pragma unroll
    for (int c = 0; c < 8; c++) s += part[c * 2048 + fm];
    ssum[fm] = s;
}

// =============== kernel C: everything after the batch softmax (one block per b) ===============
// LDS layout (bytes):
//   f1f2 bf16 [64][264] @0      (33792)   f1 then overwritten by f2
//   am   bf16 [64][40]  @33792  (5120)
//   jpart f32 [4][64]   @38912  (1024)
//   wL    f32 [64]      @39936  (256)
//   ufL   i32 [64]      @40192  (256)   (unused slot kept for alignment)
//   mskL  f32 [64]      @40448  (256)
//   scr   f32 [16]      @40704  (64)    -> 40768 dynamic
#define OFF_AM   33792
#define OFF_JP   38912
#define OFF_W    39936
#define OFF_MSK  40448
#define OFF_SCR  40704
__global__ __launch_bounds__(256, 3) void kmain(const int* __restrict__ input_u,
                                                const int* __restrict__ input_i,
                                                const int* __restrict__ input_uf,
                                                const float* __restrict__ uidW,
                                                const float* __restrict__ iidW,
                                                const float* __restrict__ i_bias,
                                                const float* __restrict__ BA,
                                                const float* __restrict__ U_omega,
                                                const float* __restrict__ att_exp1,
                                                const float* __restrict__ ak,
                                                const float* __restrict__ ssum_ws,
                                                const unsigned short* __restrict__ fe_ws,
                                                const unsigned short* __restrict__ memT_ws,
                                                const unsigned short* __restrict__ watt_ws,
                                                float* __restrict__ out) {
    extern __shared__ char smem[];
    float* jpL  = (float*)(smem + OFF_JP);
    float* wL   = (float*)(smem + OFF_W);
    float* mskL = (float*)(smem + OFF_MSK);
    float* scr  = (float*)(smem + OFF_SCR);
    const int b = blockIdx.x, t = threadIdx.x;
    const int w = t >> 6, l = t & 63, q = l >> 4;

    // early global loads (used in final phase)
    int iu = input_u[b], ii = input_i[b];
    float uidv = uidW[(size_t)iu * DIM + t];
    float iidv = iidW[(size_t)ii * DIM + t];
    float ib   = i_bias[ii];
    float ae00 = att_exp1[t * 2], ae01 = att_exp1[t * 2 + 1];
    float ae10 = att_exp1[(DIM + t) * 2], ae11 = att_exp1[(DIM + t) * 2 + 1];

    if (t < 64) {
        int uf = input_uf[b * NF + t];
        mskL[t] = (uf != USER_NUM) ? 1.0f : 0.0f;
    }
    __syncthreads();

    // ph1: att_mem = mask * exp(ak)/ssum -> LDS bf16 (A-operand of f1 GEMM)
    {
        const float4* akp = (const float4*)(ak + (size_t)b * 2048);
        const float4* sp  = (const float4*)ssum_ws;
        float4 a0 = akp[2 * t], a1 = akp[2 * t + 1];
        float4 s0 = sp[2 * t],  s1 = sp[2 * t + 1];
        float mk = mskL[t >> 2];
        float v0 = mk * __expf(a0.x) / s0.x;
        float v1 = mk * __expf(a0.y) / s0.y;
        float v2 = mk * __expf(a0.z) / s0.z;
        float v3 = mk * __expf(a0.w) / s0.w;
        float v4 = mk * __expf(a1.x) / s1.x;
        float v5 = mk * __expf(a1.y) / s1.y;
        float v6 = mk * __expf(a1.z) / s1.z;
        float v7 = mk * __expf(a1.w) / s1.w;
        uint4 pk;
        pk.x = (unsigned)f2bf(v0) | ((unsigned)f2bf(v1) << 16);
        pk.y = (unsigned)f2bf(v2) | ((unsigned)f2bf(v3) << 16);
        pk.z = (unsigned)f2bf(v4) | ((unsigned)f2bf(v5) << 16);
        pk.w = (unsigned)f2bf(v6) | ((unsigned)f2bf(v7) << 16);
        *(uint4*)(smem + OFF_AM + (t >> 2) * 80 + (t & 3) * 16) = pk;
    }
    __syncthreads();

    // ph2: f1[64f x 256d] = am[64x32] @ Mem[32x256]  (wave w owns d in [64w,64w+64))
    // Mem B-frags straight from L2-hot ws.
    {
        const uint4* mp = (const uint4*)memT_ws;   // [d][m] rows of 64B = 4 uint4
        bf16x8 aF[4];
#pragma unroll
        for (int ft = 0; ft < 4; ft++)
            aF[ft] = *(const bf16x8*)(smem + OFF_AM + (ft * 16 + (l & 15)) * 80 + q * 16);
#pragma unroll
        for (int dti = 0; dti < 4; dti++) {
            int dt = 4 * w + dti;
            bf16x8 bF = as_frag(mp[(dt * 16 + (l & 15)) * 4 + q]);
            int dcol = dt * 16 + (l & 15);
#pragma unroll
            for (int ft = 0; ft < 4; ft++) {
                f32x4 acc = {0.f, 0.f, 0.f, 0.f};
                acc = __builtin_amdgcn_mfma_f32_16x16x32_bf16(aF[ft], bF, acc, 0, 0, 0);
                int fbase = ft * 16 + q * 4;
#pragma unroll
                for (int r = 0; r < 4; r++)
                    *(unsigned short*)(smem + (fbase + r) * 528 + dcol * 2) = f2bf(acc[r]);
            }
        }
    }
    __syncthreads();

    // ph3: read fe (sequential bf16 from ws); f2 = f1 * fe (mask already folded into fe)
    {
        ushort4 feb[16];
#pragma unroll
        for (int i = 0; i < 16; i++) {
            int f = w * 16 + i;
            feb[i] = *(const ushort4*)(fe_ws + (size_t)b * 16384 + f * 256 + l * 4);
        }
#pragma unroll
        for (int i = 0; i < 16; i++) {
            int f = w * 16 + i;
            ushort4* p = (ushort4*)(smem + f * 528 + l * 8);
            ushort4 fv = *p;
            ushort4 o4;
            o4.x = f2bf(bf2f(fv.x) * bf2f(feb[i].x));
            o4.y = f2bf(bf2f(fv.y) * bf2f(feb[i].y));
            o4.z = f2bf(bf2f(fv.z) * bf2f(feb[i].z));
            o4.w = f2bf(bf2f(fv.w) * bf2f(feb[i].w));
            *p = o4;
        }
    }
    __syncthreads();

    // ph4: H = relu(f2 @ WA + BA); logits j_f = sum_a H*Uw. Wave w owns a in [64w,64w+64).
    // WA B-frags straight from L2-hot ws -> NO barriers in the kt loop.
    f32x4 acc[4][4];
    {
        f32x4 z = {0.f, 0.f, 0.f, 0.f};
#pragma unroll
        for (int ft = 0; ft < 4; ft++)
#pragma unroll
            for (int at = 0; at < 4; at++) acc[ft][at] = z;
    }
    {
        const uint4* wp = (const uint4*)watt_ws;   // [kt][a][kk]: kt*1024 + a*4 + q
        for (int kt = 0; kt < 8; kt++) {
            bf16x8 aF[4], bF[4];
#pragma unroll
            for (int ft = 0; ft < 4; ft++)
                aF[ft] = *(const bf16x8*)(smem + (ft * 16 + (l & 15)) * 528 + kt * 64 + q * 16);
#pragma unroll
            for (int at = 0; at < 4; at++)
                bF[at] = as_frag(wp[kt * 1024 + (64 * w + at * 16 + (l & 15)) * 4 + q]);
#pragma unroll
            for (int ft = 0; ft < 4; ft++)
#pragma unroll
                for (int at = 0; at < 4; at++)
                    acc[ft][at] = __builtin_amdgcn_mfma_f32_16x16x32_bf16(aF[ft], bF[at], acc[ft][at], 0, 0, 0);
        }
    }
    {
        float jp[16];
#pragma unroll
        for (int i = 0; i < 16; i++) jp[i] = 0.f;
#pragma unroll
        for (int at = 0; at < 4; at++) {
            int a = 64 * w + at * 16 + (l & 15);
            float ba = BA[a], uw = U_omega[a];
#pragma unroll
            for (int ft = 0; ft < 4; ft++)
#pragma unroll
                for (int r = 0; r < 4; r++) {
                    float h = fmaxf(acc[ft][at][r] + ba, 0.f);
                    jp[ft * 4 + r] += h * uw;
                }
        }
#pragma unroll
        for (int mask = 1; mask < 16; mask <<= 1)
#pragma unroll
            for (int i = 0; i < 16; i++) jp[i] += __shfl_xor(jp[i], mask, 64);
        if ((l & 15) == 0) {
#pragma unroll
            for (int ft = 0; ft < 4; ft++)
#pragma unroll
                for (int r = 0; r < 4; r++)
                    jpL[w * 64 + ft * 16 + q * 4 + r] = jp[ft * 4 + r];
        }
    }
    __syncthreads();

    // ph5: friend weights w_f = mask*exp(logit) / (sum + 1e-8)
    if (t < 64) {
        float logit = jpL[t] + jpL[64 + t] + jpL[128 + t] + jpL[192 + t];
        float jv = mskL[t] * __expf(logit);
        float s = jv;
#pragma unroll
        for (int o = 32; o; o >>= 1) s += __shfl_xor(s, o, 64);
        wL[t] = jv / (s + 1e-8f);
    }
    __syncthreads();

    // ph6: friend[d] = sum_f w_f * f2[f][d]
    float fr = 0.f;
#pragma unroll 8
    for (int f = 0; f < 64; f++)
        fr += wL[f] * bf2f(*(unsigned short*)(smem + f * 528 + t * 2));

    // ph7: user attention + score
    float user = uidv + fr;
    float l0 = block_reduce_sum(uidv * ae00 + user * ae10, scr);
    float l1 = block_reduce_sum(uidv * ae01 + user * ae11, scr);
    float mx = fmaxf(l0, l1);
    float e0 = __expf(l0 - mx), e1 = __expf(l1 - mx);
    float rinv = 1.0f / (e0 + e1);
    float a0w = e0 * rinv, a1w = e1 * rinv;
    float sc = block_reduce_sum((uidv * a0w + user * a1w) * iidv, scr);
    if (t == 0) out[b] = sc + ib;
}

extern "C" void kernel_launch(void* const* d_in, const int* in_sizes, int n_in,
                              void* d_out, int out_size, void* d_ws, size_t ws_size,
                              hipStream_t stream) {
    const int*   input_u  = (const int*)d_in[0];
    const int*   input_i  = (const int*)d_in[1];
    const int*   input_uf = (const int*)d_in[2];
    const float* uidW     = (const float*)d_in[3];
    const float* iidW     = (const float*)d_in[4];
    const float* i_bias   = (const float*)d_in[5];
    const float* Key      = (const float*)d_in[6];
    const float* Mem      = (const float*)d_in[7];
    const float* WA       = (const float*)d_in[8];
    const float* BA       = (const float*)d_in[9];
    const float* U_omega  = (const float*)d_in[10];
    const float* att_exp1 = (const float*)d_in[11];
    float* out = (float*)d_out;
    char* ws = (char*)d_ws;

    float*          ak   = (float*)(ws + WS_AK);
    unsigned short* fe   = (unsigned short*)(ws + WS_FE);
    unsigned short* keyT = (unsigned short*)(ws + WS_KEYT);
    unsigned short* memT = (unsigned short*)(ws + WS_MEMT);
    unsigned short* watt = (unsigned short*)(ws + WS_WATT);
    float*          part = (float*)(ws + WS_PART);
    float*          ssum = (float*)(ws + WS_SSUM);

    hipLaunchKernelGGL(kprep, dim3(320), dim3(256), 0, stream, Key, Mem, WA, keyT, memT, watt);
    hipLaunchKernelGGL(katt, dim3(BATCH), dim3(256), 35392, stream, input_u, input_uf, uidW, keyT, fe, ak);
    hipLaunchKernelGGL(ksum1, dim3(512), dim3(256), 0, stream, ak, part);
    hipLaunchKernelGGL(ksum2, dim3(8), dim3(256), 0, stream, part, ssum);
    hipLaunchKernelGGL(kmain, dim3(BATCH), dim3(256), 40768, stream, input_u, input_i, input_uf,
                       uidW, iidW, i_bias, BA, U_omega, att_exp1, ak, ssum, fe, memT, watt, out);
}